// Round 5
// baseline (122.391 us; speedup 1.0000x reference)
//
#include <hip/hip_runtime.h>
#include <hip/hip_bf16.h>
#include <math.h>

#define NN 4096
#define BB 4
// (1/64) * log2(e)  -- folds 1/sqrt(N) and exp->exp2 conversion
#define SCL 0.022542110013890054f
#define LOG2E 1.4426950408889634f

typedef __attribute__((ext_vector_type(8))) short bf16x8;
typedef __attribute__((ext_vector_type(4))) float f32x4;
typedef __attribute__((ext_vector_type(4))) short s16x4;

__device__ __forceinline__ float exp2_fast(float x) {
  float r; asm("v_exp_f32 %0, %1" : "=v"(r) : "v"(x)); return r;
}
__device__ __forceinline__ short bf16s(float x) {
  __hip_bfloat16 b = __float2bfloat16(x);
  return *(short*)&b;
}

// ---------------------------------------------------------------------------
// Kernel 1 (fused by block range):
//   blocks [0,2048):    Wh = h@W -> WhT bf16 [B][64][4096];
//                       E-tables: Eit = (2^(w1s), 2^(0.2 w1s)), Ejt likewise
//                       for w2s, where w1s/w2s = (Wh@a) * SCL.
//   blocks [2048,4096): adj int32 -> bitmask (LSB gather, no ballot).
// ---------------------------------------------------------------------------
__global__ __launch_bounds__(256)
void k_prep(const float* __restrict__ h, const float* __restrict__ W,
            const float* __restrict__ a, const int* __restrict__ adj,
            unsigned short* __restrict__ WhT, float2* __restrict__ Eit,
            float2* __restrict__ Ejt, unsigned* __restrict__ bits) {
  const int t = threadIdx.x;
  const int bi = blockIdx.x;
  if (bi >= 2048) {
    const int ti = (bi - 2048) * 256 + t;      // 0 .. 524287
    const int r = ti >> 7, g = ti & 127;       // row, 32-j word index
    const int4* __restrict__ ap = (const int4*)(adj + ((size_t)r << 12) + (g << 5));
    unsigned m = 0;
#pragma unroll
    for (int q = 0; q < 8; ++q) {
      int4 av = ap[q];
      m |= (unsigned)(av.x & 1) << (q * 4 + 0);
      m |= (unsigned)(av.y & 1) << (q * 4 + 1);
      m |= (unsigned)(av.z & 1) << (q * 4 + 2);
      m |= (unsigned)(av.w & 1) << (q * 4 + 3);
    }
    bits[(size_t)r * 128 + g] = m;
    return;
  }
  // ---- Wh path: 8 rows (same batch) per block ----
  __shared__ float sW[4096];
  __shared__ unsigned short T[64][8];
#pragma unroll
  for (int i = 0; i < 16; ++i) sW[i * 256 + t] = W[i * 256 + t];
  __syncthreads();
  const int wv = t >> 6, lane = t & 63;
  const float a1 = a[lane], a2 = a[64 + lane];
  const int row0 = bi * 8;
  for (int r = 0; r < 2; ++r) {
    const int row = row0 + wv * 2 + r;
    const float* hr = h + (size_t)row * 64;
    float acc = 0.f;
#pragma unroll
    for (int k = 0; k < 64; ++k) acc = fmaf(hr[k], sW[k * 64 + lane], acc);
    T[lane][wv * 2 + r] = (unsigned short)bf16s(acc);
    float r1 = acc * a1, r2 = acc * a2;
#pragma unroll
    for (int sft = 32; sft; sft >>= 1) { r1 += __shfl_xor(r1, sft); r2 += __shfl_xor(r2, sft); }
    if (lane == 0) {
      const float w1s = r1 * SCL, w2s = r2 * SCL;
      Eit[row] = make_float2(exp2_fast(w1s), exp2_fast(0.2f * w1s));
      Ejt[row] = make_float2(exp2_fast(w2s), exp2_fast(0.2f * w2s));
    }
  }
  __syncthreads();
  const int f = t >> 2, jp4 = t & 3;
  const int bidx = row0 >> 12, n0 = row0 & 4095;
  unsigned v = *(unsigned*)&T[f][jp4 * 2];
  *(unsigned*)(WhT + (((size_t)(bidx * 64 + f)) << 12) + n0 + jp4 * 2) = v;
}

// ---------------------------------------------------------------------------
// Kernel 2: masked-softmax attention, MFMA PV, normalized h' -> bf16 ws.
// Grid 256 = 4 b x 64 i-blocks (64 i). Block 1024 thr = 16 waves (ih, s):
// ih picks 16 i-rows, s K-splits j into 1024-wide quarters.
// P[i=jp][k=rg*8+e] built in registers from the rank-1 E-factorization:
//   p = adj ? ((E1i*E1j > 1) ? E1i*E1j : E2i*E2j) : 0      (no exp, no w2)
// Explicit 1-deep software pipeline (next-window af/E/mask prefetch regs).
// Denominator via ones-MFMA. No LDS/barriers in main loop.
// ---------------------------------------------------------------------------
__global__ __launch_bounds__(1024, 4)
void k_gat(const unsigned* __restrict__ bits,
           const unsigned short* __restrict__ WhT,
           const float2* __restrict__ Eit, const float2* __restrict__ Ejt,
           unsigned short* __restrict__ hprime) {
  __shared__ float hp[4][16][68];   // [ih][i][f]+pad combine buffer, 17 KB
  __shared__ float ls[4][64];       // denom partials [s][i-local]

  const int t = threadIdx.x;
  const int w = t >> 6, lane = t & 63;
  const int ih = w >> 2, s = w & 3;
  const int b = blockIdx.x >> 6;
  const int i0 = (blockIdx.x & 63) * 64;
  const int jp = lane & 15;    // A-frag row (f-local) / P row (i)
  const int rg = lane >> 4;    // k-group

  const int i = i0 + ih * 16 + jp;
  const float2 ei = Eit[b * NN + i];
  const float E1i = ei.x, E2i = ei.y;
  const unsigned* __restrict__ bitrow = bits + (size_t)i * 128 + s * 32;
  const unsigned short* __restrict__ abase =
      WhT + (((size_t)(b * 64 + jp)) << 12) + rg * 8;
  const float* __restrict__ ejbase = (const float*)(Ejt + b * NN);

  f32x4 acc[4];
#pragma unroll
  for (int ft = 0; ft < 4; ++ft) acc[ft] = (f32x4){0.f, 0.f, 0.f, 0.f};
  f32x4 accd = (f32x4){0.f, 0.f, 0.f, 0.f};
  bf16x8 ones;
#pragma unroll
  for (int e = 0; e < 8; ++e) ones[e] = (short)0x3F80;

  // prologue: load window 0
  bf16x8 afc[4]; f32x4 qc[4]; unsigned mwc;
  {
    const int j0 = s * 1024;
#pragma unroll
    for (int ft = 0; ft < 4; ++ft)
      afc[ft] = *(const bf16x8*)(abase + (ft << 16) + j0);
    const f32x4* ej = (const f32x4*)(ejbase + 2 * (j0 + rg * 8));
#pragma unroll
    for (int qq = 0; qq < 4; ++qq) qc[qq] = ej[qq];
    mwc = bitrow[0];
  }

  for (int jt = 0; jt < 32; ++jt) {
    // prefetch window jt+1 (jt=31 over-reads into adjacent ws buffers: safe,
    // values discarded)
    bf16x8 afn[4]; f32x4 qn[4]; unsigned mwn;
    const int j1 = s * 1024 + jt * 32 + 32;
#pragma unroll
    for (int ft = 0; ft < 4; ++ft)
      afn[ft] = *(const bf16x8*)(abase + (ft << 16) + j1);
    const f32x4* ej = (const f32x4*)(ejbase + 2 * (j1 + rg * 8));
#pragma unroll
    for (int qq = 0; qq < 4; ++qq) qn[qq] = ej[qq];
    mwn = bitrow[jt + 1];

    // scores for current window: 8 entries, no transcendentals
    const unsigned mb = mwc >> (rg * 8);
    bf16x8 p;
#pragma unroll
    for (int e = 0; e < 8; ++e) {
      const float e1 = qc[e >> 1][(e & 1) * 2];
      const float e2 = qc[e >> 1][(e & 1) * 2 + 1];
      const float P1 = E1i * e1;
      const float P2 = E2i * e2;
      float pv = P1 > 1.0f ? P1 : P2;        // leaky branch select
      pv = ((mb >> e) & 1u) ? pv : 0.0f;     // adjacency mask
      p[e] = bf16s(pv);
    }
    accd = __builtin_amdgcn_mfma_f32_16x16x32_bf16(ones, p, accd, 0, 0, 0);
#pragma unroll
    for (int ft = 0; ft < 4; ++ft)
      acc[ft] = __builtin_amdgcn_mfma_f32_16x16x32_bf16(afc[ft], p, acc[ft], 0, 0, 0);
#pragma unroll
    for (int ft = 0; ft < 4; ++ft) afc[ft] = afn[ft];
#pragma unroll
    for (int qq = 0; qq < 4; ++qq) qc[qq] = qn[qq];
    mwc = mwn;
  }

  // denom partials (D rows identical; take reg 0 at rg==0)
  if (rg == 0) ls[s][ih * 16 + jp] = accd[0];

  // combine h' partials across s (serialized phases; disjoint [ih] regions)
  if (s == 3) {
#pragma unroll
    for (int ft = 0; ft < 4; ++ft)
      *(f32x4*)&hp[ih][jp][ft * 16 + rg * 4] = acc[ft];
  }
  __syncthreads();
  if (s == 2) {
#pragma unroll
    for (int ft = 0; ft < 4; ++ft) {
      f32x4 tv = *(f32x4*)&hp[ih][jp][ft * 16 + rg * 4];
      *(f32x4*)&hp[ih][jp][ft * 16 + rg * 4] = tv + acc[ft];
    }
  }
  __syncthreads();
  if (s == 1) {
#pragma unroll
    for (int ft = 0; ft < 4; ++ft) {
      f32x4 tv = *(f32x4*)&hp[ih][jp][ft * 16 + rg * 4];
      *(f32x4*)&hp[ih][jp][ft * 16 + rg * 4] = tv + acc[ft];
    }
  }
  __syncthreads();
  if (s == 0) {
#pragma unroll
    for (int ft = 0; ft < 4; ++ft) {
      f32x4 tv = *(f32x4*)&hp[ih][jp][ft * 16 + rg * 4];
      *(f32x4*)&hp[ih][jp][ft * 16 + rg * 4] = tv + acc[ft];
    }
  }
  __syncthreads();

  // normalize + bf16 store: thread -> (i-local = t>>4, f-group = (t&15)*4)
  const int il = t >> 4, fo = (t & 15) * 4;
  const float ltot = ls[0][il] + ls[1][il] + ls[2][il] + ls[3][il];
  const float invl = 1.f / ltot;
  const int ihh = il >> 4, ii = il & 15;
  s16x4 pk;
#pragma unroll
  for (int r = 0; r < 4; ++r)
    pk[r] = bf16s(hp[ihh][ii][fo + r] * invl);
  *(s16x4*)(hprime + (((size_t)(b * NN + i0 + il)) << 6) + fo) = pk;
}

// ---------------------------------------------------------------------------
// Kernel 3: BatchNorm over (b,f) per node + residual + ELU.
// ---------------------------------------------------------------------------
__global__ __launch_bounds__(256)
void k_bn(const float* __restrict__ h, const unsigned short* __restrict__ hprime,
          const float* __restrict__ gamma, const float* __restrict__ beta,
          float* __restrict__ out) {
  __shared__ float bnp[8][4][2];
  const int t = threadIdx.x;
  const int w = t >> 6, lane = t & 63;   // w = batch
  const int i0 = blockIdx.x * 8;
  float x[8];
#pragma unroll
  for (int ii = 0; ii < 8; ++ii) {
    unsigned u = (unsigned)hprime[(((size_t)(w * NN + i0 + ii)) << 6) + lane] << 16;
    float xv = *(float*)&u;
    x[ii] = xv;
    float s1 = xv, s2 = xv * xv;
#pragma unroll
    for (int m = 32; m; m >>= 1) { s1 += __shfl_xor(s1, m); s2 += __shfl_xor(s2, m); }
    if (lane == 0) { bnp[ii][w][0] = s1; bnp[ii][w][1] = s2; }
  }
  __syncthreads();
#pragma unroll
  for (int ii = 0; ii < 8; ++ii) {
    const float t1 = bnp[ii][0][0] + bnp[ii][1][0] + bnp[ii][2][0] + bnp[ii][3][0];
    const float t2 = bnp[ii][0][1] + bnp[ii][1][1] + bnp[ii][2][1] + bnp[ii][3][1];
    const float mean = t1 * (1.f / 256.f);
    const float var  = t2 * (1.f / 256.f) - mean * mean;
    const float sc = gamma[i0 + ii] * rsqrtf(var + 1e-5f);
    const float bt = beta[i0 + ii];
    const size_t off = (((size_t)(w * NN + i0 + ii)) << 6) + lane;
    float o = sc * (x[ii] - mean) + bt + h[off];
    o = o > 0.f ? o : exp2_fast(o * LOG2E) - 1.f;
    out[off] = o;
  }
}

// ---------------------------------------------------------------------------
extern "C" void kernel_launch(void* const* d_in, const int* in_sizes, int n_in,
                              void* d_out, int out_size, void* d_ws, size_t ws_size,
                              hipStream_t stream) {
  (void)in_sizes; (void)n_in; (void)out_size; (void)ws_size;
  const float* h     = (const float*)d_in[0];
  const int*   adj   = (const int*)d_in[1];
  const float* W     = (const float*)d_in[2];
  const float* a     = (const float*)d_in[3];
  const float* gamma = (const float*)d_in[4];
  const float* beta  = (const float*)d_in[5];
  float* out = (float*)d_out;

  char* ws = (char*)d_ws;
  unsigned short* WhT = (unsigned short*)ws;                 // 2 MB @ 0
  unsigned* bits = (unsigned*)(ws + (2u << 20));             // 2 MB @ 2MB
  float2* Eit = (float2*)(ws + (4u << 20));                  // 128 KB @ 4MB
  float2* Ejt = (float2*)(ws + (4u << 20) + (128u << 10));   // 128 KB
  unsigned short* hprime = (unsigned short*)(ws + (4u << 20) + (256u << 10)); // 2 MB

  k_prep<<<4096, 256, 0, stream>>>(h, W, a, adj, WhT, Eit, Ejt, bits);
  k_gat<<<256, 1024, 0, stream>>>(bits, WhT, Eit, Ejt, hprime);
  k_bn<<<512, 256, 0, stream>>>(h, hprime, gamma, beta, out);
}

// Round 6
// 121.829 us; speedup vs baseline: 1.0046x; 1.0046x over previous
//
#include <hip/hip_runtime.h>
#include <hip/hip_bf16.h>
#include <math.h>

#define NN 4096
#define BB 4
// (1/64) * log2(e)  -- folds 1/sqrt(N) and exp->exp2 conversion
#define SCL 0.022542110013890054f
#define LOG2E 1.4426950408889634f

typedef __attribute__((ext_vector_type(8))) short bf16x8;
typedef __attribute__((ext_vector_type(4))) float f32x4;
typedef __attribute__((ext_vector_type(4))) short s16x4;

__device__ __forceinline__ float exp2_fast(float x) {
  float r; asm("v_exp_f32 %0, %1" : "=v"(r) : "v"(x)); return r;
}
__device__ __forceinline__ short bf16s(float x) {
  __hip_bfloat16 b = __float2bfloat16(x);
  return *(short*)&b;
}

// ---------------------------------------------------------------------------
// Kernel 1 (fused by block range):
//   blocks [0,2048):    Wh = h@W -> WhT bf16 [B][64][4096];
//                       E-tables: Eit = (2^(w1s), 2^(0.2 w1s)), Ejt likewise
//                       for w2s, where w1s/w2s = (Wh@a) * SCL.
//   blocks [2048,4096): adj int32 -> bitmask (LSB gather, no ballot).
// ---------------------------------------------------------------------------
__global__ __launch_bounds__(256)
void k_prep(const float* __restrict__ h, const float* __restrict__ W,
            const float* __restrict__ a, const int* __restrict__ adj,
            unsigned short* __restrict__ WhT, float2* __restrict__ Eit,
            float2* __restrict__ Ejt, unsigned* __restrict__ bits) {
  const int t = threadIdx.x;
  const int bi = blockIdx.x;
  if (bi >= 2048) {
    const int ti = (bi - 2048) * 256 + t;      // 0 .. 524287
    const int r = ti >> 7, g = ti & 127;       // row, 32-j word index
    const int4* __restrict__ ap = (const int4*)(adj + ((size_t)r << 12) + (g << 5));
    unsigned m = 0;
#pragma unroll
    for (int q = 0; q < 8; ++q) {
      int4 av = ap[q];
      m |= (unsigned)(av.x & 1) << (q * 4 + 0);
      m |= (unsigned)(av.y & 1) << (q * 4 + 1);
      m |= (unsigned)(av.z & 1) << (q * 4 + 2);
      m |= (unsigned)(av.w & 1) << (q * 4 + 3);
    }
    bits[(size_t)r * 128 + g] = m;
    return;
  }
  // ---- Wh path: 8 rows (same batch) per block ----
  __shared__ float sW[4096];
  __shared__ unsigned short T[64][8];
#pragma unroll
  for (int i = 0; i < 16; ++i) sW[i * 256 + t] = W[i * 256 + t];
  __syncthreads();
  const int wv = t >> 6, lane = t & 63;
  const float a1 = a[lane], a2 = a[64 + lane];
  const int row0 = bi * 8;
  for (int r = 0; r < 2; ++r) {
    const int row = row0 + wv * 2 + r;
    const float* hr = h + (size_t)row * 64;
    float acc = 0.f;
#pragma unroll
    for (int k = 0; k < 64; ++k) acc = fmaf(hr[k], sW[k * 64 + lane], acc);
    T[lane][wv * 2 + r] = (unsigned short)bf16s(acc);
    float r1 = acc * a1, r2 = acc * a2;
#pragma unroll
    for (int sft = 32; sft; sft >>= 1) { r1 += __shfl_xor(r1, sft); r2 += __shfl_xor(r2, sft); }
    if (lane == 0) {
      const float w1s = r1 * SCL, w2s = r2 * SCL;
      Eit[row] = make_float2(exp2_fast(w1s), exp2_fast(0.2f * w1s));
      Ejt[row] = make_float2(exp2_fast(w2s), exp2_fast(0.2f * w2s));
    }
  }
  __syncthreads();
  const int f = t >> 2, jp4 = t & 3;
  const int bidx = row0 >> 12, n0 = row0 & 4095;
  unsigned v = *(unsigned*)&T[f][jp4 * 2];
  *(unsigned*)(WhT + (((size_t)(bidx * 64 + f)) << 12) + n0 + jp4 * 2) = v;
}

// ---------------------------------------------------------------------------
// Kernel 2: masked-softmax attention, MFMA PV, normalized h' -> bf16 ws.
// Grid 512 = 4 b x 128 i-blocks (32 i rows). Block 512 thr = 8 waves (ih, s):
// ih picks 16 i-rows, s K-splits j into 1024-wide quarters -> 32 windows/wave.
// P[i=jp][k=rg*8+e] in registers via the rank-1 max factorization:
//   p = adj ? max(E1i*E1j, E2i*E2j) : 0     (exactly exp2(leaky(s)); no exp)
// Denominator via ones-MFMA (idle matrix pipe). No LDS/barriers in main loop.
// 512-thr blocks + grid 512 -> 2 blocks/CU = 4 waves/SIMD for latency hiding;
// no hand prefetch (r5 lesson: compiler re-sinks it and tanks VGPRs).
// ---------------------------------------------------------------------------
__global__ __launch_bounds__(512, 4)
void k_gat(const unsigned* __restrict__ bits,
           const unsigned short* __restrict__ WhT,
           const float2* __restrict__ Eit, const float2* __restrict__ Ejt,
           unsigned short* __restrict__ hprime) {
  __shared__ float hp[2][16][68];   // [ih][i][f]+pad combine buffer, 8.7 KB
  __shared__ float ls[4][32];       // denom partials [s][i-local]

  const int t = threadIdx.x;
  const int w = t >> 6, lane = t & 63;
  const int ih = w >> 2, s = w & 3;
  const int b = blockIdx.x >> 7;
  const int i0 = (blockIdx.x & 127) * 32;
  const int jp = lane & 15;    // A-frag row (f-local) / P row (i)
  const int rg = lane >> 4;    // k-group

  const int i = i0 + ih * 16 + jp;
  const float2 ei = Eit[b * NN + i];
  const float E1i = ei.x, E2i = ei.y;
  const unsigned* __restrict__ bitrow = bits + (size_t)i * 128 + s * 32;
  const unsigned short* __restrict__ abase =
      WhT + (((size_t)(b * 64 + jp)) << 12) + rg * 8;
  const float* __restrict__ ejbase = (const float*)(Ejt + b * NN);

  f32x4 acc[4];
#pragma unroll
  for (int ft = 0; ft < 4; ++ft) acc[ft] = (f32x4){0.f, 0.f, 0.f, 0.f};
  f32x4 accd = (f32x4){0.f, 0.f, 0.f, 0.f};
  bf16x8 ones;
#pragma unroll
  for (int e = 0; e < 8; ++e) ones[e] = (short)0x3F80;

  for (int jt = 0; jt < 32; ++jt) {
    const int j0 = s * 1024 + jt * 32;
    bf16x8 af[4];
#pragma unroll
    for (int ft = 0; ft < 4; ++ft)
      af[ft] = *(const bf16x8*)(abase + (ft << 16) + j0);
    const f32x4* __restrict__ ej = (const f32x4*)(ejbase + 2 * (j0 + rg * 8));
    const f32x4 q0 = ej[0], q1 = ej[1], q2 = ej[2], q3 = ej[3];
    const unsigned mb = bitrow[jt] >> (rg * 8);

    // 8 P entries: qX holds (E1j, E2j) pairs for 2 j's each
    bf16x8 p;
#pragma unroll
    for (int e = 0; e < 8; ++e) {
      const f32x4 qq = (e < 2) ? q0 : (e < 4) ? q1 : (e < 6) ? q2 : q3;
      const float E1j = qq[(e & 1) * 2];
      const float E2j = qq[(e & 1) * 2 + 1];
      float pv = fmaxf(E1i * E1j, E2i * E2j);   // == exp2(leaky(score))
      pv = ((mb >> e) & 1u) ? pv : 0.0f;        // adjacency mask
      p[e] = bf16s(pv);
    }
    accd = __builtin_amdgcn_mfma_f32_16x16x32_bf16(ones, p, accd, 0, 0, 0);
#pragma unroll
    for (int ft = 0; ft < 4; ++ft)
      acc[ft] = __builtin_amdgcn_mfma_f32_16x16x32_bf16(af[ft], p, acc[ft], 0, 0, 0);
  }

  // denom partials (D rows identical; take reg 0 at rg==0)
  if (rg == 0) ls[s][ih * 16 + jp] = accd[0];

  // combine h' partials across s (serialized phases; disjoint [ih] regions)
  if (s == 3) {
#pragma unroll
    for (int ft = 0; ft < 4; ++ft)
      *(f32x4*)&hp[ih][jp][ft * 16 + rg * 4] = acc[ft];
  }
  __syncthreads();
  if (s == 2) {
#pragma unroll
    for (int ft = 0; ft < 4; ++ft) {
      f32x4 tv = *(f32x4*)&hp[ih][jp][ft * 16 + rg * 4];
      *(f32x4*)&hp[ih][jp][ft * 16 + rg * 4] = tv + acc[ft];
    }
  }
  __syncthreads();
  if (s == 1) {
#pragma unroll
    for (int ft = 0; ft < 4; ++ft) {
      f32x4 tv = *(f32x4*)&hp[ih][jp][ft * 16 + rg * 4];
      *(f32x4*)&hp[ih][jp][ft * 16 + rg * 4] = tv + acc[ft];
    }
  }
  __syncthreads();
  if (s == 0) {
#pragma unroll
    for (int ft = 0; ft < 4; ++ft) {
      f32x4 tv = *(f32x4*)&hp[ih][jp][ft * 16 + rg * 4];
      *(f32x4*)&hp[ih][jp][ft * 16 + rg * 4] = tv + acc[ft];
    }
  }
  __syncthreads();

  // normalize + bf16 store: thread -> (i-local = t>>4, f-group = (t&15)*4)
  const int il = t >> 4, fo = (t & 15) * 4;
  const float ltot = ls[0][il] + ls[1][il] + ls[2][il] + ls[3][il];
  const float invl = 1.f / ltot;
  const int ihh = il >> 4, ii = il & 15;
  s16x4 pk;
#pragma unroll
  for (int r = 0; r < 4; ++r)
    pk[r] = bf16s(hp[ihh][ii][fo + r] * invl);
  *(s16x4*)(hprime + (((size_t)(b * NN + i0 + il)) << 6) + fo) = pk;
}

// ---------------------------------------------------------------------------
// Kernel 3: BatchNorm over (b,f) per node + residual + ELU.
// ---------------------------------------------------------------------------
__global__ __launch_bounds__(256)
void k_bn(const float* __restrict__ h, const unsigned short* __restrict__ hprime,
          const float* __restrict__ gamma, const float* __restrict__ beta,
          float* __restrict__ out) {
  __shared__ float bnp[8][4][2];
  const int t = threadIdx.x;
  const int w = t >> 6, lane = t & 63;   // w = batch
  const int i0 = blockIdx.x * 8;
  float x[8];
#pragma unroll
  for (int ii = 0; ii < 8; ++ii) {
    unsigned u = (unsigned)hprime[(((size_t)(w * NN + i0 + ii)) << 6) + lane] << 16;
    float xv = *(float*)&u;
    x[ii] = xv;
    float s1 = xv, s2 = xv * xv;
#pragma unroll
    for (int m = 32; m; m >>= 1) { s1 += __shfl_xor(s1, m); s2 += __shfl_xor(s2, m); }
    if (lane == 0) { bnp[ii][w][0] = s1; bnp[ii][w][1] = s2; }
  }
  __syncthreads();
#pragma unroll
  for (int ii = 0; ii < 8; ++ii) {
    const float t1 = bnp[ii][0][0] + bnp[ii][1][0] + bnp[ii][2][0] + bnp[ii][3][0];
    const float t2 = bnp[ii][0][1] + bnp[ii][1][1] + bnp[ii][2][1] + bnp[ii][3][1];
    const float mean = t1 * (1.f / 256.f);
    const float var  = t2 * (1.f / 256.f) - mean * mean;
    const float sc = gamma[i0 + ii] * rsqrtf(var + 1e-5f);
    const float bt = beta[i0 + ii];
    const size_t off = (((size_t)(w * NN + i0 + ii)) << 6) + lane;
    float o = sc * (x[ii] - mean) + bt + h[off];
    o = o > 0.f ? o : exp2_fast(o * LOG2E) - 1.f;
    out[off] = o;
  }
}

// ---------------------------------------------------------------------------
extern "C" void kernel_launch(void* const* d_in, const int* in_sizes, int n_in,
                              void* d_out, int out_size, void* d_ws, size_t ws_size,
                              hipStream_t stream) {
  (void)in_sizes; (void)n_in; (void)out_size; (void)ws_size;
  const float* h     = (const float*)d_in[0];
  const int*   adj   = (const int*)d_in[1];
  const float* W     = (const float*)d_in[2];
  const float* a     = (const float*)d_in[3];
  const float* gamma = (const float*)d_in[4];
  const float* beta  = (const float*)d_in[5];
  float* out = (float*)d_out;

  char* ws = (char*)d_ws;
  unsigned short* WhT = (unsigned short*)ws;                 // 2 MB @ 0
  unsigned* bits = (unsigned*)(ws + (2u << 20));             // 2 MB @ 2MB
  float2* Eit = (float2*)(ws + (4u << 20));                  // 128 KB @ 4MB
  float2* Ejt = (float2*)(ws + (4u << 20) + (128u << 10));   // 128 KB
  unsigned short* hprime = (unsigned short*)(ws + (4u << 20) + (256u << 10)); // 2 MB

  k_prep<<<4096, 256, 0, stream>>>(h, W, a, adj, WhT, Eit, Ejt, bits);
  k_gat<<<512, 512, 0, stream>>>(bits, WhT, Eit, Ejt, hprime);
  k_bn<<<512, 256, 0, stream>>>(h, hprime, gamma, beta, out);
}

// Round 7
// 68.240 us; speedup vs baseline: 1.7935x; 1.7853x over previous
//
#include <hip/hip_runtime.h>
#include <hip/hip_bf16.h>
#include <math.h>

#define NN 4096
#define BB 4
// (1/64) * log2(e)  -- folds 1/sqrt(N) and exp->exp2 conversion
#define SCL 0.022542110013890054f
#define LOG2E 1.4426950408889634f

typedef __attribute__((ext_vector_type(8))) short bf16x8;
typedef __attribute__((ext_vector_type(4))) float f32x4;
typedef __attribute__((ext_vector_type(4))) short s16x4;

__device__ __forceinline__ float exp2_fast(float x) {
  float r; asm("v_exp_f32 %0, %1" : "=v"(r) : "v"(x)); return r;
}
__device__ __forceinline__ short bf16s(float x) {
  __hip_bfloat16 b = __float2bfloat16(x);
  return *(short*)&b;
}

// ---------------------------------------------------------------------------
// Kernel 1 (fused by block range):
//   blocks [0,2048):    Wh = h@W -> fragment-major WhTf (see k_gat); E-tables.
//   blocks [2048,4096): adj -> TRANSPOSED bitmask bitsT[g][i] (g = 32-j word).
//     block = 256 i-rows x 1 g: reads 128 B/thread, writes 1 KB coalesced.
// ---------------------------------------------------------------------------
__global__ __launch_bounds__(256)
void k_prep(const float* __restrict__ h, const float* __restrict__ W,
            const float* __restrict__ a, const int* __restrict__ adj,
            unsigned short* __restrict__ WhTf, float2* __restrict__ Eit,
            float2* __restrict__ Ejt, unsigned* __restrict__ bitsT) {
  const int t = threadIdx.x;
  const int bi = blockIdx.x;
  if (bi >= 2048) {
    const int ci = bi - 2048;              // 0..2047
    const int g = ci >> 4;                 // 0..127  (32-j word index)
    const int i = (ci & 15) * 256 + t;     // 0..4095 (node row)
    const int4* __restrict__ ap = (const int4*)(adj + ((size_t)i << 12) + (g << 5));
    unsigned m = 0;
#pragma unroll
    for (int q = 0; q < 8; ++q) {
      int4 av = ap[q];
      m |= (unsigned)(av.x & 1) << (q * 4 + 0);
      m |= (unsigned)(av.y & 1) << (q * 4 + 1);
      m |= (unsigned)(av.z & 1) << (q * 4 + 2);
      m |= (unsigned)(av.w & 1) << (q * 4 + 3);
    }
    bitsT[((size_t)g << 12) + i] = m;
    return;
  }
  // ---- Wh path: 8 rows (same batch) per block ----
  __shared__ float sW[4096];
  __shared__ unsigned short T[64][8];
#pragma unroll
  for (int i = 0; i < 16; ++i) sW[i * 256 + t] = W[i * 256 + t];
  __syncthreads();
  const int wv = t >> 6, lane = t & 63;
  const float a1 = a[lane], a2 = a[64 + lane];
  const int row0 = bi * 8;
  for (int r = 0; r < 2; ++r) {
    const int row = row0 + wv * 2 + r;
    const float* hr = h + (size_t)row * 64;
    float acc = 0.f;
#pragma unroll
    for (int k = 0; k < 64; ++k) acc = fmaf(hr[k], sW[k * 64 + lane], acc);
    T[lane][wv * 2 + r] = (unsigned short)bf16s(acc);
    float r1 = acc * a1, r2 = acc * a2;
#pragma unroll
    for (int sft = 32; sft; sft >>= 1) { r1 += __shfl_xor(r1, sft); r2 += __shfl_xor(r2, sft); }
    if (lane == 0) {
      const float w1s = r1 * SCL, w2s = r2 * SCL;
      Eit[row] = make_float2(exp2_fast(w1s), exp2_fast(0.2f * w1s));
      Ejt[row] = make_float2(exp2_fast(w2s), exp2_fast(0.2f * w2s));
    }
  }
  __syncthreads();
  // fragment-major store: element (b, ft, w32, lane=rg*16+jp, e) holds
  // Wh[n = w32*32 + rg*8 + e][f = ft*16 + jp]. Block's 8 nodes share
  // (w32, rg) since row0 is 8-aligned. Thread t: f = t>>2, e-pair = (t&3)*2.
  const int f = t >> 2, jp4 = t & 3;
  const int b = row0 >> 12, n0 = row0 & 4095;
  const int w32 = n0 >> 5, rgq = (n0 >> 3) & 3;
  unsigned v = *(unsigned*)&T[f][jp4 * 2];
  unsigned short* dst = WhTf +
      ((((size_t)(b * 4 + (f >> 4)) << 7) + w32) << 9) +   // 1KB frag block
      ((rgq * 16 + (f & 15)) << 3) + jp4 * 2;              // lane*8 + e
  *(unsigned*)dst = v;
}

// ---------------------------------------------------------------------------
// Kernel 2: masked-softmax attention, MFMA PV, normalized h' -> bf16 ws.
// Grid 512 = 4 b x 128 i-blocks (32 i rows). Block 512 thr = 8 waves (ih, s):
// ih picks 16 i-rows, s K-splits j into 1024-wide quarters -> 32 windows/wave.
// P[i=jp][k=rg*8+e] in registers via the rank-1 max factorization:
//   p = adj ? max(E1i*E1j, E2i*E2j) : 0     (exactly exp2(leaky(s)); no exp)
// All hot loads are wave-coalesced: af = one contiguous 1KB fragment-major
// block; mask = 16 consecutive dwords of bitsT (rg-broadcast); ej broadcast.
// Denominator via ones-MFMA. No LDS/barriers in main loop.
// ---------------------------------------------------------------------------
__global__ __launch_bounds__(512, 4)
void k_gat(const unsigned* __restrict__ bitsT,
           const unsigned short* __restrict__ WhTf,
           const float2* __restrict__ Eit, const float2* __restrict__ Ejt,
           unsigned short* __restrict__ hprime) {
  __shared__ float hp[2][16][68];   // [ih][i][f]+pad combine buffer, 8.7 KB
  __shared__ float ls[4][32];       // denom partials [s][i-local]

  const int t = threadIdx.x;
  const int w = t >> 6, lane = t & 63;
  const int ih = w >> 2, s = w & 3;
  const int b = blockIdx.x >> 7;
  const int i0 = (blockIdx.x & 127) * 32;
  const int jp = lane & 15;    // A-frag f-local / P row (i)
  const int rg = lane >> 4;    // k-group

  const int i = i0 + ih * 16 + jp;
  const float2 ei = Eit[b * NN + i];
  const float E1i = ei.x, E2i = ei.y;
  // mask: word (s*32 + jt) of row i, transposed layout
  const unsigned* __restrict__ bitbase = bitsT + (((size_t)s * 32) << 12) + i;
  // A-frags: contiguous 1KB per (ft, window); windows stride 1KB (streaming)
  const unsigned short* __restrict__ abase =
      WhTf + ((((size_t)b * 4) << 7) + s * 32) * 512 + lane * 8;
  const float* __restrict__ ejbase = (const float*)(Ejt + b * NN);

  f32x4 acc[4];
#pragma unroll
  for (int ft = 0; ft < 4; ++ft) acc[ft] = (f32x4){0.f, 0.f, 0.f, 0.f};
  f32x4 accd = (f32x4){0.f, 0.f, 0.f, 0.f};
  bf16x8 ones;
#pragma unroll
  for (int e = 0; e < 8; ++e) ones[e] = (short)0x3F80;

#pragma unroll 2
  for (int jt = 0; jt < 32; ++jt) {
    const int j0 = s * 1024 + jt * 32;
    bf16x8 af[4];
#pragma unroll
    for (int ft = 0; ft < 4; ++ft)
      af[ft] = *(const bf16x8*)(abase + ((ft << 7) + jt) * 512);
    const f32x4* __restrict__ ej = (const f32x4*)(ejbase + 2 * (j0 + rg * 8));
    const f32x4 q0 = ej[0], q1 = ej[1], q2 = ej[2], q3 = ej[3];
    const unsigned mb = bitbase[(size_t)jt << 12] >> (rg * 8);

    // 8 P entries: qX holds (E1j, E2j) pairs for 2 j's each
    bf16x8 p;
#pragma unroll
    for (int e = 0; e < 8; ++e) {
      const f32x4 qq = (e < 2) ? q0 : (e < 4) ? q1 : (e < 6) ? q2 : q3;
      const float E1j = qq[(e & 1) * 2];
      const float E2j = qq[(e & 1) * 2 + 1];
      float pv = fmaxf(E1i * E1j, E2i * E2j);   // == exp2(leaky(score))
      pv = ((mb >> e) & 1u) ? pv : 0.0f;        // adjacency mask
      p[e] = bf16s(pv);
    }
    accd = __builtin_amdgcn_mfma_f32_16x16x32_bf16(ones, p, accd, 0, 0, 0);
#pragma unroll
    for (int ft = 0; ft < 4; ++ft)
      acc[ft] = __builtin_amdgcn_mfma_f32_16x16x32_bf16(af[ft], p, acc[ft], 0, 0, 0);
  }

  // denom partials (D rows identical; take reg 0 at rg==0)
  if (rg == 0) ls[s][ih * 16 + jp] = accd[0];

  // combine h' partials across s (serialized phases; disjoint [ih] regions)
  if (s == 3) {
#pragma unroll
    for (int ft = 0; ft < 4; ++ft)
      *(f32x4*)&hp[ih][jp][ft * 16 + rg * 4] = acc[ft];
  }
  __syncthreads();
  if (s == 2) {
#pragma unroll
    for (int ft = 0; ft < 4; ++ft) {
      f32x4 tv = *(f32x4*)&hp[ih][jp][ft * 16 + rg * 4];
      *(f32x4*)&hp[ih][jp][ft * 16 + rg * 4] = tv + acc[ft];
    }
  }
  __syncthreads();
  if (s == 1) {
#pragma unroll
    for (int ft = 0; ft < 4; ++ft) {
      f32x4 tv = *(f32x4*)&hp[ih][jp][ft * 16 + rg * 4];
      *(f32x4*)&hp[ih][jp][ft * 16 + rg * 4] = tv + acc[ft];
    }
  }
  __syncthreads();
  if (s == 0) {
#pragma unroll
    for (int ft = 0; ft < 4; ++ft) {
      f32x4 tv = *(f32x4*)&hp[ih][jp][ft * 16 + rg * 4];
      *(f32x4*)&hp[ih][jp][ft * 16 + rg * 4] = tv + acc[ft];
    }
  }
  __syncthreads();

  // normalize + bf16 store: thread -> (i-local = t>>4, f-group = (t&15)*4)
  const int il = t >> 4, fo = (t & 15) * 4;
  const float ltot = ls[0][il] + ls[1][il] + ls[2][il] + ls[3][il];
  const float invl = 1.f / ltot;
  const int ihh = il >> 4, ii = il & 15;
  s16x4 pk;
#pragma unroll
  for (int r = 0; r < 4; ++r)
    pk[r] = bf16s(hp[ihh][ii][fo + r] * invl);
  *(s16x4*)(hprime + (((size_t)(b * NN + i0 + il)) << 6) + fo) = pk;
}

// ---------------------------------------------------------------------------
// Kernel 3: BatchNorm over (b,f) per node + residual + ELU.
// ---------------------------------------------------------------------------
__global__ __launch_bounds__(256)
void k_bn(const float* __restrict__ h, const unsigned short* __restrict__ hprime,
          const float* __restrict__ gamma, const float* __restrict__ beta,
          float* __restrict__ out) {
  __shared__ float bnp[8][4][2];
  const int t = threadIdx.x;
  const int w = t >> 6, lane = t & 63;   // w = batch
  const int i0 = blockIdx.x * 8;
  float x[8];
#pragma unroll
  for (int ii = 0; ii < 8; ++ii) {
    unsigned u = (unsigned)hprime[(((size_t)(w * NN + i0 + ii)) << 6) + lane] << 16;
    float xv = *(float*)&u;
    x[ii] = xv;
    float s1 = xv, s2 = xv * xv;
#pragma unroll
    for (int m = 32; m; m >>= 1) { s1 += __shfl_xor(s1, m); s2 += __shfl_xor(s2, m); }
    if (lane == 0) { bnp[ii][w][0] = s1; bnp[ii][w][1] = s2; }
  }
  __syncthreads();
#pragma unroll
  for (int ii = 0; ii < 8; ++ii) {
    const float t1 = bnp[ii][0][0] + bnp[ii][1][0] + bnp[ii][2][0] + bnp[ii][3][0];
    const float t2 = bnp[ii][0][1] + bnp[ii][1][1] + bnp[ii][2][1] + bnp[ii][3][1];
    const float mean = t1 * (1.f / 256.f);
    const float var  = t2 * (1.f / 256.f) - mean * mean;
    const float sc = gamma[i0 + ii] * rsqrtf(var + 1e-5f);
    const float bt = beta[i0 + ii];
    const size_t off = (((size_t)(w * NN + i0 + ii)) << 6) + lane;
    float o = sc * (x[ii] - mean) + bt + h[off];
    o = o > 0.f ? o : exp2_fast(o * LOG2E) - 1.f;
    out[off] = o;
  }
}

// ---------------------------------------------------------------------------
extern "C" void kernel_launch(void* const* d_in, const int* in_sizes, int n_in,
                              void* d_out, int out_size, void* d_ws, size_t ws_size,
                              hipStream_t stream) {
  (void)in_sizes; (void)n_in; (void)out_size; (void)ws_size;
  const float* h     = (const float*)d_in[0];
  const int*   adj   = (const int*)d_in[1];
  const float* W     = (const float*)d_in[2];
  const float* a     = (const float*)d_in[3];
  const float* gamma = (const float*)d_in[4];
  const float* beta  = (const float*)d_in[5];
  float* out = (float*)d_out;

  char* ws = (char*)d_ws;
  unsigned short* WhTf = (unsigned short*)ws;                // 2 MB @ 0
  unsigned* bitsT = (unsigned*)(ws + (2u << 20));            // 2 MB @ 2MB
  float2* Eit = (float2*)(ws + (4u << 20));                  // 128 KB @ 4MB
  float2* Ejt = (float2*)(ws + (4u << 20) + (128u << 10));   // 128 KB
  unsigned short* hprime = (unsigned short*)(ws + (4u << 20) + (256u << 10)); // 2 MB

  k_prep<<<4096, 256, 0, stream>>>(h, W, a, adj, WhTf, Eit, Ejt, bitsT);
  k_gat<<<512, 512, 0, stream>>>(bitsT, WhTf, Eit, Ejt, hprime);
  k_bn<<<512, 256, 0, stream>>>(h, hprime, gamma, beta, out);
}

// Round 8
// 65.968 us; speedup vs baseline: 1.8553x; 1.0344x over previous
//
#include <hip/hip_runtime.h>
#include <hip/hip_bf16.h>
#include <math.h>

#define NN 4096
// (1/64) * log2(e)  -- folds 1/sqrt(N) and exp->exp2 conversion
#define SCL 0.022542110013890054f
#define LOG2E 1.4426950408889634f

typedef __attribute__((ext_vector_type(8))) short bf16x8;
typedef __attribute__((ext_vector_type(4))) float f32x4;
typedef __attribute__((ext_vector_type(4))) short s16x4;

__device__ __forceinline__ float exp2_fast(float x) {
  float r; asm("v_exp_f32 %0, %1" : "=v"(r) : "v"(x)); return r;
}
__device__ __forceinline__ short bf16s(float x) {
  __hip_bfloat16 b = __float2bfloat16(x);
  return *(short*)&b;
}
__device__ __forceinline__ float bf2f(unsigned short u) {
  unsigned v = (unsigned)u << 16; return *(float*)&v;
}
__device__ __forceinline__ void gload16(const void* g, void* l) {
  __builtin_amdgcn_global_load_lds(
      (const __attribute__((address_space(1))) unsigned*)g,
      (__attribute__((address_space(3))) unsigned*)l, 16, 0, 0);
}

// ---------------------------------------------------------------------------
// Kernel 1 (fused by block range):
//   blocks [0,2048):    Wh = h@W -> fragment-major WhTf; E-tables (r7 layout).
//   blocks [2048,2560): adj -> row-major bits[i][g] via LDS nibble transpose:
//     coalesced int4 reads -> nibble bytes in LDS -> 128 thr pack -> coalesced
//     word stores. 8 rows/block.
// ---------------------------------------------------------------------------
__global__ __launch_bounds__(256)
void k_prep(const float* __restrict__ h, const float* __restrict__ W,
            const float* __restrict__ a, const int* __restrict__ adj,
            unsigned short* __restrict__ WhTf, float2* __restrict__ Eit,
            float2* __restrict__ Ejt, unsigned* __restrict__ bits) {
  __shared__ float sW[4096];
  __shared__ unsigned short T[64][8];
  __shared__ unsigned char nb[1024];
  const int t = threadIdx.x;
  const int bi = blockIdx.x;
  if (bi >= 2048) {
    const int i0r = (bi - 2048) * 8;
    for (int r = 0; r < 8; ++r) {
      const int4* __restrict__ rowp = (const int4*)(adj + ((size_t)(i0r + r) << 12));
#pragma unroll
      for (int q = 0; q < 4; ++q) {
        int4 v = rowp[t + 256 * q];
        nb[t + 256 * q] = (unsigned char)((v.x & 1) | ((v.y & 1) << 1) |
                                          ((v.z & 1) << 2) | ((v.w & 1) << 3));
      }
      __syncthreads();
      if (t < 128) {
        unsigned long long nn = *(const unsigned long long*)&nb[t * 8];
        unsigned wd = 0;
#pragma unroll
        for (int k = 0; k < 8; ++k)
          wd |= ((unsigned)(nn >> (8 * k)) & 0xFu) << (4 * k);
        bits[((size_t)(i0r + r) << 7) + t] = wd;
      }
      __syncthreads();
    }
    return;
  }
  // ---- Wh path: 8 rows (same batch) per block ----
#pragma unroll
  for (int i = 0; i < 16; ++i) sW[i * 256 + t] = W[i * 256 + t];
  __syncthreads();
  const int wv = t >> 6, lane = t & 63;
  const float a1 = a[lane], a2 = a[64 + lane];
  const int row0 = bi * 8;
  for (int r = 0; r < 2; ++r) {
    const int row = row0 + wv * 2 + r;
    const float* hr = h + (size_t)row * 64;
    float acc = 0.f;
#pragma unroll
    for (int k = 0; k < 64; ++k) acc = fmaf(hr[k], sW[k * 64 + lane], acc);
    T[lane][wv * 2 + r] = (unsigned short)bf16s(acc);
    float r1 = acc * a1, r2 = acc * a2;
#pragma unroll
    for (int sft = 32; sft; sft >>= 1) { r1 += __shfl_xor(r1, sft); r2 += __shfl_xor(r2, sft); }
    if (lane == 0) {
      const float w1s = r1 * SCL, w2s = r2 * SCL;
      Eit[row] = make_float2(exp2_fast(w1s), exp2_fast(0.2f * w1s));
      Ejt[row] = make_float2(exp2_fast(w2s), exp2_fast(0.2f * w2s));
    }
  }
  __syncthreads();
  // fragment-major store (r7-validated): (b, ft, g, lane=rg*16+jp, e) holds
  // Wh[n = g*32 + rg*8 + e][f = ft*16 + jp].
  const int f = t >> 2, jp4 = t & 3;
  const int b = row0 >> 12, n0 = row0 & 4095;
  const int g32 = n0 >> 5, rgq = (n0 >> 3) & 3;
  unsigned v = *(unsigned*)&T[f][jp4 * 2];
  unsigned short* dst = WhTf +
      ((((size_t)(b * 4 + (f >> 4)) << 7) + g32) << 9) +
      ((rgq * 16 + (f & 15)) << 3) + jp4 * 2;
  *(unsigned*)dst = v;
}

// ---------------------------------------------------------------------------
// Kernel 2: masked-softmax attention partials via MFMA with block-cooperative
// LDS staging. Grid = nc x 4b x 64 i-blocks (64 rows). Block 256 thr = 4
// waves; ALL waves sweep the same j-windows (32 j each, W windows per chunk);
// wave w owns i-rows [i0+16w, i0+16w+16) and stages the ft=w A-fragment.
// One-time LDS stages: mask (padded [64][33], conflict-free) + Ej chunk.
// Per window: global_load_lds(16B) next A-frags -> dbuf; ds_read current;
// p = adj ? max(E1i*E1j, E2i*E2j) : 0 (rank-1 max factorization, exact);
// 5 MFMA (4 PV + ones-denominator). One barrier per window (T3-mini).
// Outputs: unnormalized bf16 partial h' + f32 denom partial per chunk.
// ---------------------------------------------------------------------------
__global__ __launch_bounds__(256, 4)
void k_gat(const unsigned* __restrict__ bits,
           const unsigned short* __restrict__ WhTf,
           const float2* __restrict__ Eit, const float* __restrict__ Ejt,
           unsigned short* __restrict__ Pp, float* __restrict__ lsp, int W) {
  extern __shared__ char smem[];
  unsigned short* abuf = (unsigned short*)smem;          // 2 x 4 x 1024 B
  unsigned* mlds = (unsigned*)(smem + 8192);             // 64 x 33 u32 = 8448 B
  float* ejlds = (float*)(smem + 8192 + 8448);           // W*64 floats

  const int t = threadIdx.x;
  const int w = t >> 6, lane = t & 63;
  const int jp = lane & 15, rg = lane >> 4;
  const int bid = blockIdx.x;
  const int c = bid >> 8;
  const int b = (bid >> 6) & 3;
  const int i0 = (bid & 63) * 64;
  const int g0 = c * W;

  // one-time: mask rows -> padded LDS
  {
    const int row = t >> 2;
    const unsigned* src = bits + ((size_t)(i0 + row) << 7) + g0;
    for (int g = (t & 3); g < W; g += 4) mlds[row * 33 + g] = src[g];
  }
  // one-time: Ej chunk -> LDS (W*64 floats)
  {
    const float4* src = (const float4*)(Ejt + ((size_t)b * NN + (size_t)g0 * 32) * 2);
    float4* dst = (float4*)ejlds;
    const int cnt = W * 16;
    for (int k2 = t; k2 < cnt; k2 += 256) dst[k2] = src[k2];
  }
  // stage window 0: wave w stages fragment ft=w
  const size_t fbase = ((size_t)(b * 4 + w) << 7) + g0;   // fragment index base
  gload16(WhTf + ((fbase + 0) << 9) + lane * 8, abuf + w * 512 + lane * 8);

  const float2 ei = Eit[b * NN + i0 + w * 16 + jp];
  const float E1i = ei.x, E2i = ei.y;

  f32x4 acc[4];
#pragma unroll
  for (int ft = 0; ft < 4; ++ft) acc[ft] = (f32x4){0.f, 0.f, 0.f, 0.f};
  f32x4 accd = (f32x4){0.f, 0.f, 0.f, 0.f};
  bf16x8 ones;
#pragma unroll
  for (int e = 0; e < 8; ++e) ones[e] = (short)0x3F80;

  __syncthreads();   // window-0 stage + one-time stages complete

  for (int jt = 0; jt < W; ++jt) {
    const int cur = jt & 1;
    // stage next window's A-frags (jt==W-1 over-reads <=1KB into bits: unused)
    gload16(WhTf + ((fbase + jt + 1) << 9) + lane * 8,
            abuf + (cur ^ 1) * 2048 + w * 512 + lane * 8);

    // current window from LDS
    const f32x4* __restrict__ ejp = (const f32x4*)(ejlds + jt * 64 + rg * 16);
    const f32x4 q0 = ejp[0], q1 = ejp[1], q2 = ejp[2], q3 = ejp[3];
    const unsigned mb = mlds[(w * 16 + jp) * 33 + jt] >> (rg * 8);
    bf16x8 af[4];
#pragma unroll
    for (int ft = 0; ft < 4; ++ft)
      af[ft] = *(const bf16x8*)(abuf + cur * 2048 + ft * 512 + lane * 8);

    bf16x8 p;
#pragma unroll
    for (int e = 0; e < 8; ++e) {
      const f32x4 qq = (e < 2) ? q0 : (e < 4) ? q1 : (e < 6) ? q2 : q3;
      const float E1j = qq[(e & 1) * 2];
      const float E2j = qq[(e & 1) * 2 + 1];
      float pv = fmaxf(E1i * E1j, E2i * E2j);   // == exp2(leaky(score))
      pv = ((mb >> e) & 1u) ? pv : 0.0f;        // adjacency mask
      p[e] = bf16s(pv);
    }
    accd = __builtin_amdgcn_mfma_f32_16x16x32_bf16(ones, p, accd, 0, 0, 0);
#pragma unroll
    for (int ft = 0; ft < 4; ++ft)
      acc[ft] = __builtin_amdgcn_mfma_f32_16x16x32_bf16(af[ft], p, acc[ft], 0, 0, 0);

    __syncthreads();   // stage(jt+1) done (vmcnt in barrier) + buffer handoff
  }

  // store partials: acc[ft][r] = D[f=ft*16+rg*4+r][i = i0+w*16+jp]
  const size_t obase = (((size_t)(c * 4 + b) * NN) + i0 + w * 16 + jp) * 64;
#pragma unroll
  for (int ft = 0; ft < 4; ++ft) {
    s16x4 pk;
#pragma unroll
    for (int r = 0; r < 4; ++r) pk[r] = bf16s(acc[ft][r]);
    *(s16x4*)(Pp + obase + ft * 16 + rg * 4) = pk;
  }
  if (rg == 0)
    lsp[(size_t)(c * 4 + b) * NN + i0 + w * 16 + jp] = accd[0];
}

// ---------------------------------------------------------------------------
// Kernel 3: combine chunk partials, normalize, BatchNorm + residual + ELU.
// ---------------------------------------------------------------------------
__global__ __launch_bounds__(256)
void k_bn(const float* __restrict__ h, const unsigned short* __restrict__ Pp,
          const float* __restrict__ lsp, const float* __restrict__ gamma,
          const float* __restrict__ beta, float* __restrict__ out, int nc) {
  __shared__ float bnp[8][4][2];
  const int t = threadIdx.x;
  const int w = t >> 6, lane = t & 63;   // w = batch
  const int i0 = blockIdx.x * 8;
  float x[8];
#pragma unroll
  for (int ii = 0; ii < 8; ++ii) {
    const int i = i0 + ii;
    float xv = 0.f, lt = 0.f;
    for (int cc = 0; cc < nc; ++cc) {
      xv += bf2f(Pp[((size_t)(cc * 4 + w) * NN + i) * 64 + lane]);
      lt += lsp[(size_t)(cc * 4 + w) * NN + i];
    }
    xv /= lt;
    x[ii] = xv;
    float s1 = xv, s2 = xv * xv;
#pragma unroll
    for (int m = 32; m; m >>= 1) { s1 += __shfl_xor(s1, m); s2 += __shfl_xor(s2, m); }
    if (lane == 0) { bnp[ii][w][0] = s1; bnp[ii][w][1] = s2; }
  }
  __syncthreads();
#pragma unroll
  for (int ii = 0; ii < 8; ++ii) {
    const float t1 = bnp[ii][0][0] + bnp[ii][1][0] + bnp[ii][2][0] + bnp[ii][3][0];
    const float t2 = bnp[ii][0][1] + bnp[ii][1][1] + bnp[ii][2][1] + bnp[ii][3][1];
    const float mean = t1 * (1.f / 256.f);
    const float var  = t2 * (1.f / 256.f) - mean * mean;
    const float sc = gamma[i0 + ii] * rsqrtf(var + 1e-5f);
    const float bt = beta[i0 + ii];
    const size_t off = (((size_t)(w * NN + i0 + ii)) << 6) + lane;
    float o = sc * (x[ii] - mean) + bt + h[off];
    o = o > 0.f ? o : exp2_fast(o * LOG2E) - 1.f;
    out[off] = o;
  }
}

// ---------------------------------------------------------------------------
extern "C" void kernel_launch(void* const* d_in, const int* in_sizes, int n_in,
                              void* d_out, int out_size, void* d_ws, size_t ws_size,
                              hipStream_t stream) {
  (void)in_sizes; (void)n_in; (void)out_size;
  const float* h     = (const float*)d_in[0];
  const int*   adj   = (const int*)d_in[1];
  const float* W     = (const float*)d_in[2];
  const float* a     = (const float*)d_in[3];
  const float* gamma = (const float*)d_in[4];
  const float* beta  = (const float*)d_in[5];
  float* out = (float*)d_out;

  char* ws = (char*)d_ws;
  unsigned short* WhTf = (unsigned short*)ws;                    // 2 MB @ 0
  unsigned* bits = (unsigned*)(ws + (2u << 20));                 // 2 MB @ 2M
  float2* Eit = (float2*)(ws + (4u << 20));                      // 128 KB
  float2* Ejt = (float2*)(ws + (4u << 20) + (128u << 10));       // 128 KB
  float* lsp = (float*)(ws + (4u << 20) + (256u << 10));         // <=256 KB
  unsigned short* Pp = (unsigned short*)(ws + (4u << 20) + (512u << 10)); // nc*2MB

  const size_t base = (4u << 20) + (512u << 10);
  int nc = (ws_size >= base + (8u << 20)) ? 4
         : (ws_size >= base + (4u << 20)) ? 2 : 1;
  const int Wn = 128 / nc;
  const size_t smem = 8192 + 8448 + (size_t)Wn * 256;

  k_prep<<<2560, 256, 0, stream>>>(h, W, a, adj, WhTf, Eit, Ejt, bits);
  k_gat<<<nc * 256, 256, smem, stream>>>(bits, WhTf, Eit, (const float*)Ejt,
                                         Pp, lsp, Wn);
  k_bn<<<512, 256, 0, stream>>>(h, Pp, lsp, gamma, beta, out, nc);
}